// Round 9
// baseline (218.490 us; speedup 1.0000x reference)
//
#include <hip/hip_runtime.h>
#include <cstdint>
#include <cstddef>
#include <math.h>

typedef uint16_t bf16;  // raw bf16 bits
typedef __attribute__((ext_vector_type(8))) __bf16 bf16x8;
typedef __attribute__((ext_vector_type(2))) float f32x2;
typedef __attribute__((ext_vector_type(4))) float f32x4;
typedef __attribute__((ext_vector_type(16))) float f32x16;

#define MFMA16(a,b,c) __builtin_amdgcn_mfma_f32_16x16x32_bf16((a),(b),(c),0,0,0)
#define MFMA32(a,b,c) __builtin_amdgcn_mfma_f32_32x32x16_bf16((a),(b),(c),0,0,0)

__device__ __forceinline__ uint16_t f2bf(float f){
  uint32_t u = __float_as_uint(f);
  return (uint16_t)((u + 0x7fffu + ((u >> 16) & 1u)) >> 16);
}
__device__ __forceinline__ uint32_t pk2(float lo, float hi){
  return (uint32_t)f2bf(lo) | ((uint32_t)f2bf(hi) << 16);
}

__device__ __forceinline__ void gload_lds16(const void* g, void* l){
  __builtin_amdgcn_global_load_lds((const __attribute__((address_space(1))) void*)g,
                                   (__attribute__((address_space(3))) void*)l, 16, 0, 0);
}

// ---------------- elementwise fp32 -> bf16 ----------------
__global__ void k_convert(const float* __restrict__ in, bf16* __restrict__ out, int n){
  int i = (blockIdx.x * 256 + threadIdx.x) * 4;
  if (i >= n) return;
  float4 v = *reinterpret_cast<const float4*>(in + i);
  uint32_t lo = pk2(v.x, v.y);
  uint32_t hi = pk2(v.z, v.w);
  uint2 pkv = make_uint2(lo, hi);
  *reinterpret_cast<uint2*>(out + i) = pkv;
}

// ---------------- W [R][C] f32 -> Wt [C][R] bf16, 64x64 tile, vectorized ----------------
__global__ void k_transposeW(const float* __restrict__ in, bf16* __restrict__ out, int R, int C){
  __shared__ float tile[64][65];
  int c0 = blockIdx.x * 64, r0 = blockIdx.y * 64;
  int t = threadIdx.x;
  int fx = t & 15, fy = t >> 4;
  #pragma unroll
  for (int i = 0; i < 4; i++){
    int r = fy + i*16;
    float4 v = *reinterpret_cast<const float4*>(in + (size_t)(r0 + r)*C + c0 + fx*4);
    tile[r][fx*4+0] = v.x; tile[r][fx*4+1] = v.y;
    tile[r][fx*4+2] = v.z; tile[r][fx*4+3] = v.w;
  }
  __syncthreads();
  int gx = t & 7, gy = t >> 3;
  #pragma unroll
  for (int i = 0; i < 2; i++){
    int c = gy + i*32;
    int rr = gx*8;
    union { bf16 h[8]; uint4 u; } pk_;
    #pragma unroll
    for (int j = 0; j < 8; j++) pk_.h[j] = f2bf(tile[rr+j][c]);
    *reinterpret_cast<uint4*>(out + (size_t)(c0 + c)*R + r0 + rr) = pk_.u;
  }
}

// ---------------- 8-phase GEMM core: BM=128, BN=256, BK=64, 512 thr / 8 waves of 64x64 ----------------
// A row-major [M][2048], Bt row-major [N][2048]. LDS 96KB: A dbuf 2x16KB @0, B dbuf 2x32KB @32768.
// Rows of both LDS tiles are 128B, 16B-slot XOR swizzle phys = log ^ (row&7).
// Per K-tile: 4 phases (C-quadrant each): {8 ds_read_b128; staging issues; barrier; lgkmcnt(0);
// setprio(1); 8 MFMA16; setprio(0); [q3: vmcnt(0)]; barrier}. Loads stay in flight across barriers.
__device__ __forceinline__ void gemm8_core(
    const bf16* __restrict__ Abase, const bf16* __restrict__ Btbase,
    char* lds, f32x4 acc[4][4])
{
  const int tid = threadIdx.x;
  const int wid = tid >> 6, lane = tid & 63;
  const int wr = wid >> 2, wc = wid & 3;
  const int lr = lane & 15, lg = lane >> 4;
  const f32x4 vzero = {0.f, 0.f, 0.f, 0.f};
  #pragma unroll
  for (int m = 0; m < 4; m++)
    #pragma unroll
    for (int n = 0; n < 4; n++)
      acc[m][n] = vzero;

  // staging sources (pre-swizzled for linear gload_lds dest)
  int srcA[2], srcB[4];
  #pragma unroll
  for (int i = 0; i < 2; i++){
    int db = i*8192 + tid*16;
    int row = db >> 7, sp = (db >> 4) & 7, sl = sp ^ (row & 7);
    srcA[i] = row*2048 + sl*8;
  }
  #pragma unroll
  for (int i = 0; i < 4; i++){
    int db = i*8192 + tid*16;
    int row = db >> 7, sp = (db >> 4) & 7, sl = sp ^ (row & 7);
    srcB[i] = row*2048 + sl*8;
  }
  const int dOf = wid*1024;

  // LDS read byte-addresses (within one buffer)
  int aAddr[4][2], bAddr[4][2];
  #pragma unroll
  for (int m = 0; m < 4; m++){
    int row = wr*64 + m*16 + lr;
    #pragma unroll
    for (int ks = 0; ks < 2; ks++)
      aAddr[m][ks] = row*128 + (((ks*4 + lg) ^ (row & 7)) << 4);
  }
  #pragma unroll
  for (int n = 0; n < 4; n++){
    int row = wc*64 + n*16 + lr;
    #pragma unroll
    for (int ks = 0; ks < 2; ks++)
      bAddr[n][ks] = 32768 + row*128 + (((ks*4 + lg) ^ (row & 7)) << 4);
  }

  // prologue: stage K-tile 0 into buf 0, drain, barrier
  #pragma unroll
  for (int i = 0; i < 2; i++) gload_lds16(Abase + srcA[i], lds + i*8192 + dOf);
  #pragma unroll
  for (int i = 0; i < 4; i++) gload_lds16(Btbase + srcB[i], lds + 32768 + i*8192 + dOf);
  asm volatile("s_waitcnt vmcnt(0)" ::: "memory");
  __builtin_amdgcn_s_barrier();

  for (int t = 0; t < 32; t++){
    const int ct = t & 1;
    const int nx = ct ^ 1;
    const int aOff = ct*16384, bOff = ct*32768;
    const bf16* An = Abase + (t+1)*64;
    const bf16* Bn = Btbase + (t+1)*64;
    #pragma unroll
    for (int q = 0; q < 4; q++){
      const int qm = q >> 1, qn = q & 1;
      // ds-load this phase's register subtile (8 x b128)
      bf16x8 af[2][2], bfv[2][2];
      #pragma unroll
      for (int mm = 0; mm < 2; mm++)
        #pragma unroll
        for (int ks = 0; ks < 2; ks++)
          af[mm][ks] = *reinterpret_cast<const bf16x8*>(lds + aOff + aAddr[qm*2+mm][ks]);
      #pragma unroll
      for (int nn = 0; nn < 2; nn++)
        #pragma unroll
        for (int ks = 0; ks < 2; ks++)
          bfv[nn][ks] = *reinterpret_cast<const bf16x8*>(lds + bOff + bAddr[qn*2+nn][ks]);
      // issue next-tile staging (spread over phases 0..2), in flight across barriers
      if (t < 31){
        if (q == 0){
          gload_lds16(An + srcA[0], lds + nx*16384 + dOf);
          gload_lds16(An + srcA[1], lds + nx*16384 + 8192 + dOf);
        } else if (q == 1){
          gload_lds16(Bn + srcB[0], lds + 32768 + nx*32768 + dOf);
          gload_lds16(Bn + srcB[1], lds + 32768 + nx*32768 + 8192 + dOf);
        } else if (q == 2){
          gload_lds16(Bn + srcB[2], lds + 32768 + nx*32768 + 16384 + dOf);
          gload_lds16(Bn + srcB[3], lds + 32768 + nx*32768 + 24576 + dOf);
        }
      }
      __builtin_amdgcn_s_barrier();
      asm volatile("s_waitcnt lgkmcnt(0)" ::: "memory");
      __builtin_amdgcn_sched_barrier(0);
      __builtin_amdgcn_s_setprio(1);
      #pragma unroll
      for (int mm = 0; mm < 2; mm++)
        #pragma unroll
        for (int nn = 0; nn < 2; nn++)
          #pragma unroll
          for (int ks = 0; ks < 2; ks++)
            acc[qm*2+mm][qn*2+nn] = MFMA16(af[mm][ks], bfv[nn][ks], acc[qm*2+mm][qn*2+nn]);
      __builtin_amdgcn_s_setprio(0);
      if (q == 3 && t < 31)
        asm volatile("s_waitcnt vmcnt(0)" ::: "memory");  // next tile's 6 loads landed
      __builtin_amdgcn_s_barrier();
    }
  }
}

// ---------------- fused QKV projection (8-phase core; V written pre-transposed) ----------------
// grid (32, 12): by 0..7 -> Q (256-col slices), 8..9 -> K, 10..11 -> V
__global__ __launch_bounds__(512, 1) void k_qkv(
    const bf16* __restrict__ xb,
    const bf16* __restrict__ WqT, const bf16* __restrict__ WkT, const bf16* __restrict__ WvT,
    const float* __restrict__ bq, const float* __restrict__ bk, const float* __restrict__ bv,
    bf16* __restrict__ qo, bf16* __restrict__ ko, bf16* __restrict__ vtp)
{
  __shared__ __align__(16) char lds[98304];
  int by = blockIdx.y;
  const bf16* Bt; const float* bias; int mode; int y; float scale = 1.f;
  if (by < 8){       y = by;    Bt = WqT + (size_t)y*256*2048; bias = bq + y*256; mode = 0; scale = 0.18033688011112042f; } // 0.125*log2(e)
  else if (by < 10){ y = by-8;  Bt = WkT + (size_t)y*256*2048; bias = bk + y*256; mode = 1; }
  else {             y = by-10; Bt = WvT + (size_t)y*256*2048; bias = bv + y*256; mode = 2; }
  int m0 = blockIdx.x * 128;
  f32x4 acc[4][4];
  gemm8_core(xb + (size_t)m0*2048, Bt, lds, acc);
  const int tid = threadIdx.x, wid = tid >> 6, lane = tid & 63;
  const int wr = wid >> 2, wc = wid & 3, lr = lane & 15, lg = lane >> 4;
  if (mode == 2){
    // V^T: vtp[b][col][t]
    #pragma unroll
    for (int n = 0; n < 4; n++){
      int cl = wc*64 + n*16 + lr;
      float bb = bias[cl];
      #pragma unroll
      for (int m = 0; m < 4; m++){
        int row0 = m0 + wr*64 + m*16 + lg*4;
        int bi = row0 >> 11, tl = row0 & 2047;
        union { bf16 h[4]; uint2 u; } pk_;
        #pragma unroll
        for (int r = 0; r < 4; r++) pk_.h[r] = f2bf(acc[m][n][r] + bb);
        *reinterpret_cast<uint2*>(vtp + ((size_t)bi*512 + y*256 + cl)*2048 + tl) = pk_.u;
      }
    }
  } else {
    bf16* outp = (mode == 0) ? (qo + y*256) : (ko + y*256);
    int ldc = (mode == 0) ? 2048 : 512;
    #pragma unroll
    for (int n = 0; n < 4; n++){
      int col = wc*64 + n*16 + lr;
      float bb = bias[col];
      #pragma unroll
      for (int m = 0; m < 4; m++)
        #pragma unroll
        for (int r = 0; r < 4; r++){
          int row = m0 + wr*64 + m*16 + lg*4 + r;
          outp[(size_t)row*ldc + col] = f2bf((acc[m][n][r] + bb) * scale);
        }
    }
  }
}

// ---------------- O projection (8-phase core, fp32 out) ----------------
// grid (32, 8) = 256 blocks = 1/CU
__global__ __launch_bounds__(512, 1) void k_oproj(
    const bf16* __restrict__ ab, const bf16* __restrict__ WoT,
    const float* __restrict__ bo, float* __restrict__ outp)
{
  __shared__ __align__(16) char lds[98304];
  int m0 = blockIdx.x * 128, n0 = blockIdx.y * 256;
  f32x4 acc[4][4];
  gemm8_core(ab + (size_t)m0*2048, WoT + (size_t)n0*2048, lds, acc);
  const int tid = threadIdx.x, wid = tid >> 6, lane = tid & 63;
  const int wr = wid >> 2, wc = wid & 3, lr = lane & 15, lg = lane >> 4;
  #pragma unroll
  for (int n = 0; n < 4; n++){
    int col = n0 + wc*64 + n*16 + lr;
    float bb = bo[col];
    #pragma unroll
    for (int m = 0; m < 4; m++)
      #pragma unroll
      for (int r = 0; r < 4; r++){
        int row = m0 + wr*64 + m*16 + lg*4 + r;
        outp[(size_t)row*2048 + col] = acc[m][n][r] + bb;
      }
  }
}

// ---------------- flash attention v8: counted vmcnt + raw barrier, 3-buffer LDS ----------------
// grid (4 qtiles, 64 bh) = 256 blocks = 1/CU. 8 waves x 64 q-rows (2 groups), QBLK=512, KVBLK=128.
__global__ __launch_bounds__(512, 2) void k_flash(
    const bf16* __restrict__ q, const bf16* __restrict__ kmat,
    const bf16* __restrict__ vt, bf16* __restrict__ ao)
{
  __shared__ __align__(16) char lds[98304];
  const int tid = threadIdx.x;
  const int wid = tid >> 6, lane = tid & 63;
  const int l31 = lane & 31, hi = lane >> 5;
  const int bh = blockIdx.y;
  const int b = bh >> 5, hq = bh & 31, kvh = hq >> 2;
  const int qt = blockIdx.x;
  const int qrow0 = b*2048 + qt*512 + wid*64;

  // Q fragments: qf[g][t][j] = Q[q = g*32 + l31][d = 16t + 8hi + j]
  bf16x8 qf[2][4];
  #pragma unroll
  for (int g = 0; g < 2; g++){
    const bf16* qrow = q + (size_t)(qrow0 + g*32 + l31)*2048 + hq*64 + hi*8;
    #pragma unroll
    for (int t = 0; t < 4; t++)
      qf[g][t] = *reinterpret_cast<const bf16x8*>(qrow + t*16);
  }

  f32x16 oacc[2][2];
  #pragma unroll
  for (int g = 0; g < 2; g++)
    #pragma unroll
    for (int n = 0; n < 2; n++)
      #pragma unroll
      for (int r = 0; r < 16; r++) oacc[g][n][r] = 0.f;
  float rsg[2][2];
  rsg[0][0]=0.f; rsg[0][1]=0.f; rsg[1][0]=0.f; rsg[1][1]=0.f;
  const f32x16 zv = {0.f,0.f,0.f,0.f,0.f,0.f,0.f,0.f,0.f,0.f,0.f,0.f,0.f,0.f,0.f,0.f};

  // precomputed per-lane LDS read addresses within a 16KB buffer
  const int r7 = l31 & 7;
  int A[4];
  #pragma unroll
  for (int j = 0; j < 4; j++)
    A[j] = l31*128 + (((2*j + hi) ^ r7) << 4);

  const bf16* kbase = kmat + (size_t)b*2048*512 + kvh*64;
  const bf16* vbase = vt + ((size_t)b*512 + kvh*64)*2048;

  int kSrc[2], vSrc[2];
  const int dOf = wid*1024;
  #pragma unroll
  for (int i = 0; i < 2; i++){
    int kdb = i*8192 + tid*16;
    int krow = kdb >> 7, ksp = (kdb >> 4) & 7, ksl = ksp ^ (krow & 7);
    kSrc[i] = krow*512 + ksl*8;
    int o = tid*16;
    int vrow = o >> 7, vsp = (o >> 4) & 7, vsl = vsp ^ (vrow & 7);
    vSrc[i] = vrow*2048 + i*64 + vsl*8;
  }

  #define STAGE(bo, st_) do { \
    const bf16* kb_ = kbase + (size_t)(st_)*128*512; \
    const bf16* vb_ = vbase + (st_)*128; \
    gload_lds16(kb_ + kSrc[0], lds + (bo) + dOf); \
    gload_lds16(kb_ + kSrc[1], lds + (bo) + 8192 + dOf); \
    gload_lds16(vb_ + vSrc[0], lds + 49152 + (bo) + dOf); \
    gload_lds16(vb_ + vSrc[1], lds + 49152 + (bo) + 8192 + dOf); \
  } while(0)

  #define LDK(j, imm) (*reinterpret_cast<const bf16x8*>(lds + kOff + A[j] + (imm)))
  #define LDV(j, imm) (*reinterpret_cast<const bf16x8*>(lds + 49152 + kOff + A[j] + (imm)))

  STAGE(0, 0);
  STAGE(16384, 1);

  int kOff = 0;
  int sOff = 32768;
  for (int st = 0; st < 16; st++){
    if (st == 15) asm volatile("s_waitcnt vmcnt(0)" ::: "memory");
    else          asm volatile("s_waitcnt vmcnt(4)" ::: "memory");
    __builtin_amdgcn_sched_barrier(0);
    __builtin_amdgcn_s_barrier();
    __builtin_amdgcn_sched_barrier(0);
    if (st < 14){
      STAGE(sOff, st+2);
      sOff = (sOff == 32768) ? 0 : sOff + 16384;
    }

    #pragma unroll
    for (int c = 0; c < 2; c++){
      f32x16 sc[2][2];
      __builtin_amdgcn_s_setprio(1);
      #pragma unroll
      for (int t = 0; t < 4; t++){
        bf16x8 af0 = LDK(t, c*8192);
        bf16x8 af1 = LDK(t, c*8192 + 4096);
        if (t == 0){
          sc[0][0] = MFMA32(af0, qf[0][0], zv);
          sc[1][0] = MFMA32(af0, qf[1][0], zv);
          sc[0][1] = MFMA32(af1, qf[0][0], zv);
          sc[1][1] = MFMA32(af1, qf[1][0], zv);
        } else {
          sc[0][0] = MFMA32(af0, qf[0][t], sc[0][0]);
          sc[1][0] = MFMA32(af0, qf[1][t], sc[1][0]);
          sc[0][1] = MFMA32(af1, qf[0][t], sc[0][1]);
          sc[1][1] = MFMA32(af1, qf[1][t], sc[1][1]);
        }
      }
      __builtin_amdgcn_s_setprio(0);

      uint32_t pw[2][2][8];
      #pragma unroll
      for (int g = 0; g < 2; g++){
        #pragma unroll
        for (int n = 0; n < 2; n++)
          #pragma unroll
          for (int j = 0; j < 8; j++){
            float plo = __builtin_amdgcn_exp2f(sc[g][n][2*j]);
            float phi = __builtin_amdgcn_exp2f(sc[g][n][2*j+1]);
            rsg[g][j & 1] += plo + phi;
            asm("v_cvt_pk_bf16_f32 %0, %1, %2" : "=v"(pw[g][n][j]) : "v"(plo), "v"(phi));
          }
        #pragma unroll
        for (int n = 0; n < 2; n++)
          #pragma unroll
          for (int h = 0; h < 2; h++){
            asm volatile("v_permlane32_swap_b32 %0, %1" : "+v"(pw[g][n][h*4+0]), "+v"(pw[g][n][h*4+2]));
            asm volatile("v_permlane32_swap_b32 %0, %1" : "+v"(pw[g][n][h*4+1]), "+v"(pw[g][n][h*4+3]));
          }
      }

      __builtin_amdgcn_s_setprio(1);
      #pragma unroll
      for (int kk = 0; kk < 4; kk++){
        int n = kk >> 1, h = kk & 1;
        union { uint32_t w[4]; bf16x8 v; } pa0, pa1;
        #pragma unroll
        for (int w_ = 0; w_ < 4; w_++){ pa0.w[w_] = pw[0][n][h*4+w_]; pa1.w[w_] = pw[1][n][h*4+w_]; }
        #pragma unroll
        for (int nd = 0; nd < 2; nd++){
          bf16x8 vf = LDV(kk, c*8192 + nd*4096);
          oacc[0][nd] = MFMA32(pa0.v, vf, oacc[0][nd]);
          oacc[1][nd] = MFMA32(pa1.v, vf, oacc[1][nd]);
        }
      }
      __builtin_amdgcn_s_setprio(0);
    }
    kOff = (kOff == 32768) ? 0 : kOff + 16384;
  }
  #undef STAGE
  #undef LDK
  #undef LDV

  #pragma unroll
  for (int g = 0; g < 2; g++){
    float rs = rsg[g][0] + rsg[g][1];
    float l = rs + __shfl_xor(rs, 32);
    float linv = 1.f / l;
    float lv[16];
    #pragma unroll
    for (int r = 0; r < 16; r++){
      int qi = (r & 3) + 8*(r >> 2) + 4*hi;
      lv[r] = __shfl(linv, qi);
    }
    #pragma unroll
    for (int nd = 0; nd < 2; nd++)
      #pragma unroll
      for (int r = 0; r < 16; r++){
        int qi = (r & 3) + 8*(r >> 2) + 4*hi;
        int row = qrow0 + g*32 + qi;
        ao[(size_t)row*2048 + hq*64 + nd*32 + l31] = f2bf(oacc[g][nd][r] * lv[r]);
      }
  }
}

// ---------------- host launcher ----------------
extern "C" void kernel_launch(void* const* d_in, const int* in_sizes, int n_in,
                              void* d_out, int out_size, void* d_ws, size_t ws_size,
                              hipStream_t stream)
{
  const float* x  = (const float*)d_in[0];
  const float* Wq = (const float*)d_in[1];
  const float* bq = (const float*)d_in[2];
  const float* Wk = (const float*)d_in[3];
  const float* bk = (const float*)d_in[4];
  const float* Wv = (const float*)d_in[5];
  const float* bv = (const float*)d_in[6];
  const float* Wo = (const float*)d_in[7];
  const float* bo = (const float*)d_in[8];
  float* out = (float*)d_out;

  char* ws = (char*)d_ws;
  size_t off = 0;
  auto alloc = [&](size_t bytes){ char* p = ws + off; off += (bytes + 255) & ~(size_t)255; return p; };
  bf16* xb  = (bf16*)alloc(2*2048*2048*2);   // x bf16 (reused as attnout later)
  bf16* WqT = (bf16*)alloc(2048*2048*2);
  bf16* WkT = (bf16*)alloc(512*2048*2);
  bf16* WvT = (bf16*)alloc(512*2048*2);
  bf16* WoT = (bf16*)alloc(2048*2048*2);
  bf16* qb  = (bf16*)alloc(4096*2048*2);
  bf16* kb  = (bf16*)alloc((size_t)4096*512*2);
  bf16* vtb = (bf16*)alloc((size_t)4096*512*2);
  bf16* aob = xb;  // alias: x_bf16 dead after projections

  k_convert<<<8192, 256, 0, stream>>>(x, xb, 2*2048*2048);
  k_transposeW<<<dim3(32,32), 256, 0, stream>>>(Wq, WqT, 2048, 2048);
  k_transposeW<<<dim3(8,32),  256, 0, stream>>>(Wk, WkT, 2048, 512);
  k_transposeW<<<dim3(8,32),  256, 0, stream>>>(Wv, WvT, 2048, 512);
  k_transposeW<<<dim3(32,32), 256, 0, stream>>>(Wo, WoT, 2048, 2048);
  k_qkv<<<dim3(32,12), 512, 0, stream>>>(xb, WqT, WkT, WvT, bq, bk, bv, qb, kb, vtb);
  k_flash<<<dim3(4,64), 512, 0, stream>>>(qb, kb, vtb, aob);
  k_oproj<<<dim3(32,8), 512, 0, stream>>>(aob, WoT, bo, out);
}

// Round 10
// 194.316 us; speedup vs baseline: 1.1244x; 1.1244x over previous
//
#include <hip/hip_runtime.h>
#include <cstdint>
#include <cstddef>
#include <math.h>

typedef uint16_t bf16;  // raw bf16 bits
typedef __attribute__((ext_vector_type(8))) __bf16 bf16x8;
typedef __attribute__((ext_vector_type(2))) float f32x2;
typedef __attribute__((ext_vector_type(4))) float f32x4;
typedef __attribute__((ext_vector_type(16))) float f32x16;

#define MFMA16(a,b,c) __builtin_amdgcn_mfma_f32_16x16x32_bf16((a),(b),(c),0,0,0)
#define MFMA32(a,b,c) __builtin_amdgcn_mfma_f32_32x32x16_bf16((a),(b),(c),0,0,0)

__device__ __forceinline__ uint16_t f2bf(float f){
  uint32_t u = __float_as_uint(f);
  return (uint16_t)((u + 0x7fffu + ((u >> 16) & 1u)) >> 16);
}
__device__ __forceinline__ uint32_t pk2(float lo, float hi){
  return (uint32_t)f2bf(lo) | ((uint32_t)f2bf(hi) << 16);
}

__device__ __forceinline__ void gload_lds16(const void* g, void* l){
  __builtin_amdgcn_global_load_lds((const __attribute__((address_space(1))) void*)g,
                                   (__attribute__((address_space(3))) void*)l, 16, 0, 0);
}

// ---------------- elementwise fp32 -> bf16 ----------------
__global__ void k_convert(const float* __restrict__ in, bf16* __restrict__ out, int n){
  int i = (blockIdx.x * 256 + threadIdx.x) * 4;
  if (i >= n) return;
  float4 v = *reinterpret_cast<const float4*>(in + i);
  uint32_t lo = pk2(v.x, v.y);
  uint32_t hi = pk2(v.z, v.w);
  uint2 pkv = make_uint2(lo, hi);
  *reinterpret_cast<uint2*>(out + i) = pkv;
}

// ---------------- W [R][C] f32 -> Wt [C][R] bf16, 64x64 tile, vectorized ----------------
__global__ void k_transposeW(const float* __restrict__ in, bf16* __restrict__ out, int R, int C){
  __shared__ float tile[64][65];
  int c0 = blockIdx.x * 64, r0 = blockIdx.y * 64;
  int t = threadIdx.x;
  int fx = t & 15, fy = t >> 4;
  #pragma unroll
  for (int i = 0; i < 4; i++){
    int r = fy + i*16;
    float4 v = *reinterpret_cast<const float4*>(in + (size_t)(r0 + r)*C + c0 + fx*4);
    tile[r][fx*4+0] = v.x; tile[r][fx*4+1] = v.y;
    tile[r][fx*4+2] = v.z; tile[r][fx*4+3] = v.w;
  }
  __syncthreads();
  int gx = t & 7, gy = t >> 3;
  #pragma unroll
  for (int i = 0; i < 2; i++){
    int c = gy + i*32;
    int rr = gx*8;
    union { bf16 h[8]; uint4 u; } pk_;
    #pragma unroll
    for (int j = 0; j < 8; j++) pk_.h[j] = f2bf(tile[rr+j][c]);
    *reinterpret_cast<uint4*>(out + (size_t)(c0 + c)*R + r0 + rr) = pk_.u;
  }
}

// ---------------- 128x128 bf16 GEMM core (2-phase, m97 structure) ----------------
__device__ __forceinline__ void gemm128_core(
    const bf16* __restrict__ Abase, const bf16* __restrict__ Btbase,
    int lda, int ldb, int K, bf16* As, bf16* Bs, f32x4 acc[4][4])
{
  const int tid = threadIdx.x;
  const int wid = tid >> 6, lane = tid & 63;
  const int wr = wid >> 1, wc = wid & 1;
  const int lr = lane & 15, lg = lane >> 4;
  const f32x4 vzero = {0.f, 0.f, 0.f, 0.f};

  #pragma unroll
  for (int m = 0; m < 4; m++)
    #pragma unroll
    for (int n = 0; n < 4; n++)
      acc[m][n] = vzero;

  int srcA[4], srcB[4], dOff[4];
  #pragma unroll
  for (int i = 0; i < 4; i++){
    int d = i*4096 + wid*1024 + lane*16;
    int row = d >> 7, sp = (d >> 4) & 7;
    int sl = sp ^ (row & 7);
    srcA[i] = row * lda + sl * 8;
    srcB[i] = row * ldb + sl * 8;
    dOff[i] = i*4096 + wid*1024;
  }

  for (int k0 = 0; k0 < K; k0 += 64){
    #pragma unroll
    for (int i = 0; i < 4; i++)
      gload_lds16(Abase + k0 + srcA[i], (char*)As + dOff[i]);
    #pragma unroll
    for (int i = 0; i < 4; i++)
      gload_lds16(Btbase + k0 + srcB[i], (char*)Bs + dOff[i]);
    __syncthreads();
    #pragma unroll
    for (int ks = 0; ks < 2; ks++){
      bf16x8 af[4], bfr[4];
      #pragma unroll
      for (int m = 0; m < 4; m++){
        int row = wr*64 + m*16 + lr;
        int sp = (ks*4 + lg) ^ (row & 7);
        af[m] = *reinterpret_cast<const bf16x8*>(As + row*64 + sp*8);
      }
      #pragma unroll
      for (int n = 0; n < 4; n++){
        int row = wc*64 + n*16 + lr;
        int sp = (ks*4 + lg) ^ (row & 7);
        bfr[n] = *reinterpret_cast<const bf16x8*>(Bs + row*64 + sp*8);
      }
      #pragma unroll
      for (int m = 0; m < 4; m++)
        #pragma unroll
        for (int n = 0; n < 4; n++)
          acc[m][n] = MFMA16(af[m], bfr[n], acc[m][n]);
    }
    __syncthreads();
  }
}

// ---------------- 256x256 8-phase GEMM core (m201-faithful geometry) ----------------
// 512 thr / 8 waves (wm = wid>>2, wn = wid&3), per-wave C = 128x64 (acc[8][4] f32x4).
// BK=64, K=2048 (32 tiles). LDS 128KB: buf b at b*65536; A halves +0/+16384, B halves +32768/+49152.
// Rows 128B (64 bf16), 16B-slot swizzle phys = slot ^ (row&7).
// Per K-tile: 4 phases x {ds_read subtile; stage 1 half-tile (pipelined 1 tile ahead);
//   barrier; lgkmcnt(0); setprio(1); 16 MFMA16; setprio(0); [ph3: counted vmcnt]; barrier}.
// Stagger: ph0 stages A(t+1)h1, ph1 B(t+1)h0, ph2 B(t+1)h1, ph3 A(t+2)h0.
// vmcnt(2) at ph3 certifies ALL of tile t+1 landed while A(t+2)h0 stays in flight (T4).
__device__ __forceinline__ void gemm256_core(
    const bf16* __restrict__ Abase, const bf16* __restrict__ Btbase,
    char* lds, f32x4 acc[8][4])
{
  const int tid = threadIdx.x;
  const int wid = tid >> 6, lane = tid & 63;
  const int wm = wid >> 2, wn = wid & 3;
  const int lr = lane & 15, lg = lane >> 4;
  const f32x4 vzero = {0.f, 0.f, 0.f, 0.f};
  #pragma unroll
  for (int m = 0; m < 8; m++)
    #pragma unroll
    for (int n = 0; n < 4; n++)
      acc[m][n] = vzero;

  // staging source offsets (pre-swizzled; both A and B stride 2048)
  int srcH[2];
  #pragma unroll
  for (int i = 0; i < 2; i++){
    int db = i*8192 + tid*16;
    int row = db >> 7, sp = (db >> 4) & 7, sl = sp ^ (row & 7);
    srcH[i] = row*2048 + sl*8;
  }
  const int dOf = wid*1024;

  // per-lane LDS read bases (within a 64KB buffer)
  int ksl[2];
  #pragma unroll
  for (int ks = 0; ks < 2; ks++) ksl[ks] = (((ks*4 + lg) ^ (lr & 7)) << 4);
  const int aB = wm*16384 + lr*128;
  const int bB = 32768 + (wn >> 1)*16384 + (wn & 1)*8192 + lr*128;

  const bf16* Ab1 = Abase + 128*2048;   // A half-1 rows
  const bf16* Bb1 = Btbase + 128*2048;  // B half-1 rows

  #define STG_HALF(dstOff, gsrc) do { \
    gload_lds16((gsrc) + srcH[0], lds + (dstOff) + dOf); \
    gload_lds16((gsrc) + srcH[1], lds + (dstOff) + 8192 + dOf); \
  } while(0)

  // prologue: tile 0 fully + A(1)h0; counted wait leaves A(1)h0 in flight
  STG_HALF(0,     Abase);
  STG_HALF(16384, Ab1);
  STG_HALF(32768, Btbase);
  STG_HALF(49152, Bb1);
  STG_HALF(65536, Abase + 64);
  asm volatile("s_waitcnt vmcnt(2)" ::: "memory");
  __builtin_amdgcn_s_barrier();

  bf16x8 afr[4][2], bfr[4][2];
  for (int t = 0; t < 32; t++){
    const int bo = (t & 1) * 65536;
    const int nb = bo ^ 65536;

    // ---- phase 0: quadrant (0,0); reads A[0..3], B[0..1]; stage A(t+1)h1
    #pragma unroll
    for (int am = 0; am < 4; am++)
      #pragma unroll
      for (int ks = 0; ks < 2; ks++)
        afr[am][ks] = *reinterpret_cast<const bf16x8*>(lds + bo + aB + am*2048 + ksl[ks]);
    #pragma unroll
    for (int bn = 0; bn < 2; bn++)
      #pragma unroll
      for (int ks = 0; ks < 2; ks++)
        bfr[bn][ks] = *reinterpret_cast<const bf16x8*>(lds + bo + bB + bn*2048 + ksl[ks]);
    if (t < 31) STG_HALF(nb + 16384, Ab1 + (t+1)*64);
    __builtin_amdgcn_s_barrier();
    asm volatile("s_waitcnt lgkmcnt(0)" ::: "memory");
    __builtin_amdgcn_sched_barrier(0);
    __builtin_amdgcn_s_setprio(1);
    #pragma unroll
    for (int am = 0; am < 4; am++)
      #pragma unroll
      for (int bn = 0; bn < 2; bn++)
        #pragma unroll
        for (int ks = 0; ks < 2; ks++)
          acc[am][bn] = MFMA16(afr[am][ks], bfr[bn][ks], acc[am][bn]);
    __builtin_amdgcn_s_setprio(0);
    __builtin_amdgcn_s_barrier();

    // ---- phase 1: quadrant (0,1); reads B[2..3]; stage B(t+1)h0
    #pragma unroll
    for (int bn = 2; bn < 4; bn++)
      #pragma unroll
      for (int ks = 0; ks < 2; ks++)
        bfr[bn][ks] = *reinterpret_cast<const bf16x8*>(lds + bo + bB + bn*2048 + ksl[ks]);
    if (t < 31) STG_HALF(nb + 32768, Btbase + (t+1)*64);
    __builtin_amdgcn_s_barrier();
    asm volatile("s_waitcnt lgkmcnt(0)" ::: "memory");
    __builtin_amdgcn_sched_barrier(0);
    __builtin_amdgcn_s_setprio(1);
    #pragma unroll
    for (int am = 0; am < 4; am++)
      #pragma unroll
      for (int bn = 2; bn < 4; bn++)
        #pragma unroll
        for (int ks = 0; ks < 2; ks++)
          acc[am][bn] = MFMA16(afr[am][ks], bfr[bn][ks], acc[am][bn]);
    __builtin_amdgcn_s_setprio(0);
    __builtin_amdgcn_s_barrier();

    // ---- phase 2: quadrant (1,0); reads A[4..7] (reuse regs); stage B(t+1)h1
    #pragma unroll
    for (int am = 0; am < 4; am++)
      #pragma unroll
      for (int ks = 0; ks < 2; ks++)
        afr[am][ks] = *reinterpret_cast<const bf16x8*>(lds + bo + aB + (am+4)*2048 + ksl[ks]);
    if (t < 31) STG_HALF(nb + 49152, Bb1 + (t+1)*64);
    __builtin_amdgcn_s_barrier();
    asm volatile("s_waitcnt lgkmcnt(0)" ::: "memory");
    __builtin_amdgcn_sched_barrier(0);
    __builtin_amdgcn_s_setprio(1);
    #pragma unroll
    for (int am = 0; am < 4; am++)
      #pragma unroll
      for (int bn = 0; bn < 2; bn++)
        #pragma unroll
        for (int ks = 0; ks < 2; ks++)
          acc[am+4][bn] = MFMA16(afr[am][ks], bfr[bn][ks], acc[am+4][bn]);
    __builtin_amdgcn_s_setprio(0);
    __builtin_amdgcn_s_barrier();

    // ---- phase 3: quadrant (1,1); no reads; stage A(t+2)h0; counted vmcnt
    if (t < 30) STG_HALF(bo, Abase + (t+2)*64);
    __builtin_amdgcn_s_barrier();
    __builtin_amdgcn_s_setprio(1);
    #pragma unroll
    for (int am = 0; am < 4; am++)
      #pragma unroll
      for (int bn = 2; bn < 4; bn++)
        #pragma unroll
        for (int ks = 0; ks < 2; ks++)
          acc[am+4][bn] = MFMA16(afr[am][ks], bfr[bn][ks], acc[am+4][bn]);
    __builtin_amdgcn_s_setprio(0);
    if (t < 30)      asm volatile("s_waitcnt vmcnt(2)" ::: "memory");
    else if (t == 30) asm volatile("s_waitcnt vmcnt(0)" ::: "memory");
    __builtin_amdgcn_sched_barrier(0);
    __builtin_amdgcn_s_barrier();
  }
  #undef STG_HALF
}

// ---------------- fused QKV projection (256x256 8-phase core; V pre-transposed) ----------------
// grid (16, 12): y 0..7 -> Q (256-col slices), 8..9 -> K, 10..11 -> V
__global__ __launch_bounds__(512, 1) void k_qkv(
    const bf16* __restrict__ xb,
    const bf16* __restrict__ WqT, const bf16* __restrict__ WkT, const bf16* __restrict__ WvT,
    const float* __restrict__ bq, const float* __restrict__ bk, const float* __restrict__ bv,
    bf16* __restrict__ qo, bf16* __restrict__ ko, bf16* __restrict__ vtp)
{
  __shared__ __align__(16) char lds[131072];
  int by = blockIdx.y;
  const bf16* Bt; const float* bias; int mode; int y; float scale = 1.f;
  if (by < 8){       y = by;    Bt = WqT + (size_t)y*256*2048; bias = bq + y*256; mode = 0; scale = 0.18033688011112042f; } // 0.125*log2(e)
  else if (by < 10){ y = by-8;  Bt = WkT + (size_t)y*256*2048; bias = bk + y*256; mode = 1; }
  else {             y = by-10; Bt = WvT + (size_t)y*256*2048; bias = bv + y*256; mode = 2; }
  int m0 = blockIdx.x * 256;
  f32x4 acc[8][4];
  gemm256_core(xb + (size_t)m0*2048, Bt, lds, acc);
  const int tid = threadIdx.x, wid = tid >> 6, lane = tid & 63;
  const int wm = wid >> 2, wn = wid & 3, lr = lane & 15, lg = lane >> 4;
  if (mode == 2){
    // V^T: vtp[b][kvcol][t]
    #pragma unroll
    for (int bn = 0; bn < 4; bn++){
      int c = wn*64 + bn*16 + lr;
      float bb = bias[c];
      int CL = y*256 + c;
      #pragma unroll
      for (int am = 0; am < 8; am++){
        int row0 = m0 + wm*128 + am*16 + lg*4;
        int bi = row0 >> 11, tl = row0 & 2047;
        union { bf16 h[4]; uint2 u; } pk_;
        #pragma unroll
        for (int r = 0; r < 4; r++) pk_.h[r] = f2bf(acc[am][bn][r] + bb);
        *reinterpret_cast<uint2*>(vtp + ((size_t)bi*512 + CL)*2048 + tl) = pk_.u;
      }
    }
  } else {
    bf16* outp = (mode == 0) ? (qo + y*256) : (ko + y*256);
    int ldc = (mode == 0) ? 2048 : 512;
    #pragma unroll
    for (int bn = 0; bn < 4; bn++){
      int c = wn*64 + bn*16 + lr;
      float bb = bias[c];
      #pragma unroll
      for (int am = 0; am < 8; am++)
        #pragma unroll
        for (int r = 0; r < 4; r++){
          int row = m0 + wm*128 + am*16 + lg*4 + r;
          outp[(size_t)row*ldc + c] = f2bf((acc[am][bn][r] + bb) * scale);
        }
    }
  }
}

// ---------------- O projection (2-phase 128x128 core, fp32 out) ----------------
__global__ __launch_bounds__(256, 2) void k_oproj(
    const bf16* __restrict__ ab, const bf16* __restrict__ WoT,
    const float* __restrict__ bo, float* __restrict__ outp)
{
  __shared__ __align__(16) bf16 As[128*64];
  __shared__ __align__(16) bf16 Bs[128*64];
  int m0 = blockIdx.x * 128, n0 = blockIdx.y * 128;
  f32x4 acc[4][4];
  gemm128_core(ab + (size_t)m0*2048, WoT + (size_t)n0*2048, 2048, 2048, 2048, As, Bs, acc);
  const int tid = threadIdx.x, wid = tid >> 6, lane = tid & 63;
  const int wr = wid >> 1, wc = wid & 1, lr = lane & 15, lg = lane >> 4;
  #pragma unroll
  for (int n = 0; n < 4; n++){
    int col = n0 + wc*64 + n*16 + lr;
    float bb = bo[col];
    #pragma unroll
    for (int m = 0; m < 4; m++)
      #pragma unroll
      for (int r = 0; r < 4; r++){
        int row = m0 + wr*64 + m*16 + lg*4 + r;
        outp[(size_t)row*2048 + col] = acc[m][n][r] + bb;
      }
  }
}

// ---------------- flash attention v8: counted vmcnt + raw barrier, 3-buffer LDS ----------------
// grid (4 qtiles, 64 bh) = 256 blocks = 1/CU. 8 waves x 64 q-rows (2 groups), QBLK=512, KVBLK=128.
__global__ __launch_bounds__(512, 2) void k_flash(
    const bf16* __restrict__ q, const bf16* __restrict__ kmat,
    const bf16* __restrict__ vt, bf16* __restrict__ ao)
{
  __shared__ __align__(16) char lds[98304];
  const int tid = threadIdx.x;
  const int wid = tid >> 6, lane = tid & 63;
  const int l31 = lane & 31, hi = lane >> 5;
  const int bh = blockIdx.y;
  const int b = bh >> 5, hq = bh & 31, kvh = hq >> 2;
  const int qt = blockIdx.x;
  const int qrow0 = b*2048 + qt*512 + wid*64;

  bf16x8 qf[2][4];
  #pragma unroll
  for (int g = 0; g < 2; g++){
    const bf16* qrow = q + (size_t)(qrow0 + g*32 + l31)*2048 + hq*64 + hi*8;
    #pragma unroll
    for (int t = 0; t < 4; t++)
      qf[g][t] = *reinterpret_cast<const bf16x8*>(qrow + t*16);
  }

  f32x16 oacc[2][2];
  #pragma unroll
  for (int g = 0; g < 2; g++)
    #pragma unroll
    for (int n = 0; n < 2; n++)
      #pragma unroll
      for (int r = 0; r < 16; r++) oacc[g][n][r] = 0.f;
  float rsg[2][2];
  rsg[0][0]=0.f; rsg[0][1]=0.f; rsg[1][0]=0.f; rsg[1][1]=0.f;
  const f32x16 zv = {0.f,0.f,0.f,0.f,0.f,0.f,0.f,0.f,0.f,0.f,0.f,0.f,0.f,0.f,0.f,0.f};

  const int r7 = l31 & 7;
  int A[4];
  #pragma unroll
  for (int j = 0; j < 4; j++)
    A[j] = l31*128 + (((2*j + hi) ^ r7) << 4);

  const bf16* kbase = kmat + (size_t)b*2048*512 + kvh*64;
  const bf16* vbase = vt + ((size_t)b*512 + kvh*64)*2048;

  int kSrc[2], vSrc[2];
  const int dOf = wid*1024;
  #pragma unroll
  for (int i = 0; i < 2; i++){
    int kdb = i*8192 + tid*16;
    int krow = kdb >> 7, ksp = (kdb >> 4) & 7, ksl = ksp ^ (krow & 7);
    kSrc[i] = krow*512 + ksl*8;
    int o = tid*16;
    int vrow = o >> 7, vsp = (o >> 4) & 7, vsl = vsp ^ (vrow & 7);
    vSrc[i] = vrow*2048 + i*64 + vsl*8;
  }

  #define STAGE(bo, st_) do { \
    const bf16* kb_ = kbase + (size_t)(st_)*128*512; \
    const bf16* vb_ = vbase + (st_)*128; \
    gload_lds16(kb_ + kSrc[0], lds + (bo) + dOf); \
    gload_lds16(kb_ + kSrc[1], lds + (bo) + 8192 + dOf); \
    gload_lds16(vb_ + vSrc[0], lds + 49152 + (bo) + dOf); \
    gload_lds16(vb_ + vSrc[1], lds + 49152 + (bo) + 8192 + dOf); \
  } while(0)

  #define LDK(j, imm) (*reinterpret_cast<const bf16x8*>(lds + kOff + A[j] + (imm)))
  #define LDV(j, imm) (*reinterpret_cast<const bf16x8*>(lds + 49152 + kOff + A[j] + (imm)))

  STAGE(0, 0);
  STAGE(16384, 1);

  int kOff = 0;
  int sOff = 32768;
  for (int st = 0; st < 16; st++){
    if (st == 15) asm volatile("s_waitcnt vmcnt(0)" ::: "memory");
    else          asm volatile("s_waitcnt vmcnt(4)" ::: "memory");
    __builtin_amdgcn_sched_barrier(0);
    __builtin_amdgcn_s_barrier();
    __builtin_amdgcn_sched_barrier(0);
    if (st < 14){
      STAGE(sOff, st+2);
      sOff = (sOff == 32768) ? 0 : sOff + 16384;
    }

    #pragma unroll
    for (int c = 0; c < 2; c++){
      f32x16 sc[2][2];
      __builtin_amdgcn_s_setprio(1);
      #pragma unroll
      for (int t = 0; t < 4; t++){
        bf16x8 af0 = LDK(t, c*8192);
        bf16x8 af1 = LDK(t, c*8192 + 4096);
        if (t == 0){
          sc[0][0] = MFMA32(af0, qf[0][0], zv);
          sc[1][0] = MFMA32(af0, qf[1][0], zv);
          sc[0][1] = MFMA32(af1, qf[0][0], zv);
          sc[1][1] = MFMA32(af1, qf[1][0], zv);
        } else {
          sc[0][0] = MFMA32(af0, qf[0][t], sc[0][0]);
          sc[1][0] = MFMA32(af0, qf[1][t], sc[1][0]);
          sc[0][1] = MFMA32(af1, qf[0][t], sc[0][1]);
          sc[1][1] = MFMA32(af1, qf[1][t], sc[1][1]);
        }
      }
      __builtin_amdgcn_s_setprio(0);

      uint32_t pw[2][2][8];
      #pragma unroll
      for (int g = 0; g < 2; g++){
        #pragma unroll
        for (int n = 0; n < 2; n++)
          #pragma unroll
          for (int j = 0; j < 8; j++){
            float plo = __builtin_amdgcn_exp2f(sc[g][n][2*j]);
            float phi = __builtin_amdgcn_exp2f(sc[g][n][2*j+1]);
            rsg[g][j & 1] += plo + phi;
            asm("v_cvt_pk_bf16_f32 %0, %1, %2" : "=v"(pw[g][n][j]) : "v"(plo), "v"(phi));
          }
        #pragma unroll
        for (int n = 0; n < 2; n++)
          #pragma unroll
          for (int h = 0; h < 2; h++){
            asm volatile("v_permlane32_swap_b32 %0, %1" : "+v"(pw[g][n][h*4+0]), "+v"(pw[g][n][h*4+2]));
            asm volatile("v_permlane32_swap_b32 %0, %1" : "+v"(pw[g][n][h*4+1]), "+v"(pw[g][n][h*4+3]));
          }
      }

      __builtin_amdgcn_s_setprio(1);
      #pragma unroll
      for (int kk = 0; kk < 4; kk++){
        int n = kk >> 1, h = kk & 1;
        union { uint32_t w[4]; bf16x8 v; } pa0, pa1;
        #pragma unroll
        for (int w_ = 0; w_ < 4; w_++){ pa0.w[w_] = pw[0][n][h*4+w_]; pa1.w[w_] = pw[1][n][h*4+w_]; }
        #pragma unroll
        for (int nd = 0; nd < 2; nd++){
          bf16x8 vf = LDV(kk, c*8192 + nd*4096);
          oacc[0][nd] = MFMA32(pa0.v, vf, oacc[0][nd]);
          oacc[1][nd] = MFMA32(pa1.v, vf, oacc[1][nd]);
        }
      }
      __builtin_amdgcn_s_setprio(0);
    }
    kOff = (kOff == 32768) ? 0 : kOff + 16384;
  }
  #undef STAGE
  #undef LDK
  #undef LDV

  #pragma unroll
  for (int g = 0; g < 2; g++){
    float rs = rsg[g][0] + rsg[g][1];
    float l = rs + __shfl_xor(rs, 32);
    float linv = 1.f / l;
    float lv[16];
    #pragma unroll
    for (int r = 0; r < 16; r++){
      int qi = (r & 3) + 8*(r >> 2) + 4*hi;
      lv[r] = __shfl(linv, qi);
    }
    #pragma unroll
    for (int nd = 0; nd < 2; nd++)
      #pragma unroll
      for (int r = 0; r < 16; r++){
        int qi = (r & 3) + 8*(r >> 2) + 4*hi;
        int row = qrow0 + g*32 + qi;
        ao[(size_t)row*2048 + hq*64 + nd*32 + l31] = f2bf(oacc[g][nd][r] * lv[r]);
      }
  }
}

// ---------------- host launcher ----------------
extern "C" void kernel_launch(void* const* d_in, const int* in_sizes, int n_in,
                              void* d_out, int out_size, void* d_ws, size_t ws_size,
                              hipStream_t stream)
{
  const float* x  = (const float*)d_in[0];
  const float* Wq = (const float*)d_in[1];
  const float* bq = (const float*)d_in[2];
  const float* Wk = (const float*)d_in[3];
  const float* bk = (const float*)d_in[4];
  const float* Wv = (const float*)d_in[5];
  const float* bv = (const float*)d_in[6];
  const float* Wo = (const float*)d_in[7];
  const float* bo = (const float*)d_in[8];
  float* out = (float*)d_out;

  char* ws = (char*)d_ws;
  size_t off = 0;
  auto alloc = [&](size_t bytes){ char* p = ws + off; off += (bytes + 255) & ~(size_t)255; return p; };
  bf16* xb  = (bf16*)alloc(2*2048*2048*2);   // x bf16 (reused as attnout later)
  bf16* WqT = (bf16*)alloc(2048*2048*2);
  bf16* WkT = (bf16*)alloc(512*2048*2);
  bf16* WvT = (bf16*)alloc(512*2048*2);
  bf16* WoT = (bf16*)alloc(2048*2048*2);
  bf16* qb  = (bf16*)alloc(4096*2048*2);
  bf16* kb  = (bf16*)alloc((size_t)4096*512*2);
  bf16* vtb = (bf16*)alloc((size_t)4096*512*2);
  bf16* aob = xb;  // alias: x_bf16 dead after projections

  k_convert<<<8192, 256, 0, stream>>>(x, xb, 2*2048*2048);
  k_transposeW<<<dim3(32,32), 256, 0, stream>>>(Wq, WqT, 2048, 2048);
  k_transposeW<<<dim3(8,32),  256, 0, stream>>>(Wk, WkT, 2048, 512);
  k_transposeW<<<dim3(8,32),  256, 0, stream>>>(Wv, WvT, 2048, 512);
  k_transposeW<<<dim3(32,32), 256, 0, stream>>>(Wo, WoT, 2048, 2048);
  k_qkv<<<dim3(16,12), 512, 0, stream>>>(xb, WqT, WkT, WvT, bq, bk, bv, qb, kb, vtb);
  k_flash<<<dim3(4,64), 512, 0, stream>>>(qb, kb, vtb, aob);
  k_oproj<<<dim3(32,16), 256, 0, stream>>>(aob, WoT, bo, out);
}